// Round 1
// 439.352 us; speedup vs baseline: 1.0021x; 1.0021x over previous
//
#include <hip/hip_runtime.h>
#include <math.h>

#define BB 16
#define TT 512
#define VV 8000
#define BLANK 0
#define LSM 0.1f
#define W_SOFT 0.5f
#define BLOCK 256

// Kernel 0: per-batch run scan -> meta[b*T+t] = (nonblank ? label_id : -1),
// inv_nexists[b] = 1/count(nonblank). Also zeroes d_out (re-poisoned each replay).
__global__ __launch_bounds__(TT) void meta_kernel(
    const int* __restrict__ aligns,
    const int* __restrict__ xlens,
    int* __restrict__ meta,
    float* __restrict__ inv_nexists,
    float* __restrict__ out) {
  int b = blockIdx.x;
  int t = threadIdx.x;  // 512 threads, one per frame
  if (b == 0 && t == 0) out[0] = 0.0f;

  __shared__ int s[TT];
  int xlen = xlens[b];
  int a  = (t < xlen) ? aligns[b * TT + t] : BLANK;
  int ap = BLANK;
  if (t > 0) ap = ((t - 1) < xlen) ? aligns[b * TT + t - 1] : BLANK;
  int nonblank = (a != BLANK) ? 1 : 0;
  int runstart = (nonblank && (a != ap)) ? 1 : 0;

  // inclusive Hillis-Steele scan of runstart flags
  s[t] = runstart;
  __syncthreads();
  for (int off = 1; off < TT; off <<= 1) {
    int v = (t >= off) ? s[t - off] : 0;
    __syncthreads();
    s[t] += v;
    __syncthreads();
  }
  int label_id = s[t] - 1;             // >=0 whenever nonblank
  meta[b * TT + t] = nonblank ? label_id : -1;
  __syncthreads();

  // count nonblank frames
  s[t] = nonblank;
  __syncthreads();
  for (int off = TT / 2; off > 0; off >>= 1) {
    if (t < off) s[t] += s[t + off];
    __syncthreads();
  }
  if (t == 0) inv_nexists[b] = 1.0f / (float)s[0];
}

// Kernel 1: one block per (b,t) frame; blanks exit immediately.
// Row is REGISTER-staged (8 x float4 per thread) — no LDS row buffer, so
// occupancy is VGPR-bound (~8 blocks/CU) instead of LDS-bound (5 blocks/CU),
// and phases B/C read registers instead of re-sweeping LDS.
__global__ __launch_bounds__(BLOCK) void frame_kernel(
    const float* __restrict__ logits,
    const int* __restrict__ ys,
    const float* __restrict__ soft,
    const int* __restrict__ meta,
    const float* __restrict__ inv_nexists,
    float* __restrict__ out) {
  int idx = blockIdx.x;
  int lm = meta[idx];
  if (lm < 0) return;
  int b = idx / TT;

  __shared__ float red[8];

  const float* xrow = logits + (size_t)idx * VV;
  const float* srow = soft + ((size_t)(b * TT + lm)) * VV;
  int tid = threadIdx.x;
  int wid = tid >> 6;

  // uniform prefetch of the hard label and x[y] (one broadcast transaction each)
  int y = ys[b * TT + lm];
  float xy = xrow[y];

  // Phase A: global -> registers, fused max + sum
  float4 xr[8];
  float tmax = -INFINITY, tsum = 0.0f;
#pragma unroll
  for (int k = 0; k < 8; ++k) {
    int i = tid * 4 + k * (BLOCK * 4);
    if (i < VV) {
      float4 x = *(const float4*)(xrow + i);
      xr[k] = x;
      tmax = fmaxf(tmax, fmaxf(fmaxf(x.x, x.y), fmaxf(x.z, x.w)));
      tsum += (x.x + x.y) + (x.z + x.w);
    } else {
      xr[k] = make_float4(-INFINITY, -INFINITY, -INFINITY, -INFINITY);
    }
  }
  for (int off = 32; off > 0; off >>= 1) {
    tmax = fmaxf(tmax, __shfl_xor(tmax, off));
    tsum += __shfl_xor(tsum, off);
  }
  if ((tid & 63) == 0) { red[wid] = tmax; red[4 + wid] = tsum; }
  __syncthreads();
  float bmax = fmaxf(fmaxf(red[0], red[1]), fmaxf(red[2], red[3]));
  float bsum = (red[4] + red[5]) + (red[6] + red[7]);
  __syncthreads();

  // Phase B: sumexp from registers (exp(-INF - bmax) == 0, tail is harmless)
  float tse = 0.0f;
#pragma unroll
  for (int k = 0; k < 8; ++k) {
    tse += __expf(xr[k].x - bmax) + __expf(xr[k].y - bmax) +
           __expf(xr[k].z - bmax) + __expf(xr[k].w - bmax);
  }
  for (int off = 32; off > 0; off >>= 1) tse += __shfl_xor(tse, off);
  if ((tid & 63) == 0) red[wid] = tse;
  __syncthreads();
  float sumexp = (red[0] + red[1]) + (red[2] + red[3]);
  float C = bmax + logf(sumexp);   // logZ: logp[v] = x[v] - C
  __syncthreads();

  // Phase C: dot(soft_row, x - C), streaming soft row once, x from registers
  float tdot = 0.0f;
#pragma unroll
  for (int k = 0; k < 8; ++k) {
    int i = tid * 4 + k * (BLOCK * 4);
    if (i < VV) {
      float4 sv = *(const float4*)(srow + i);
      float4 x = xr[k];
      tdot += sv.x * (x.x - C) + sv.y * (x.y - C) +
              sv.z * (x.z - C) + sv.w * (x.w - C);
    }
  }
  for (int off = 32; off > 0; off >>= 1) tdot += __shfl_xor(tdot, off);
  if ((tid & 63) == 0) red[wid] = tdot;
  __syncthreads();

  if (tid == 0) {
    float dot = (red[0] + red[1]) + (red[2] + red[3]);
    float logp_y = xy - C;
    float sum_lp = bsum - (float)VV * C;
    float frame_hard = (1.0f - LSM) * logp_y +
                       (LSM / (float)(VV - 1)) * (sum_lp - logp_y);
    float val = W_SOFT * dot + (1.0f - W_SOFT) * frame_hard;
    atomicAdd(out, -val * inv_nexists[b] * (1.0f / (float)BB));
  }
}

extern "C" void kernel_launch(void* const* d_in, const int* in_sizes, int n_in,
                              void* d_out, int out_size, void* d_ws, size_t ws_size,
                              hipStream_t stream) {
  const float* logits = (const float*)d_in[0];
  const int*   ys     = (const int*)d_in[1];
  const float* soft   = (const float*)d_in[2];
  const int*   aligns = (const int*)d_in[3];
  const int*   xlens  = (const int*)d_in[4];
  // d_in[5] = ylens: unused by the reference math

  int*   meta  = (int*)d_ws;
  float* inv_n = (float*)((char*)d_ws + (size_t)BB * TT * sizeof(int));
  float* out   = (float*)d_out;

  meta_kernel<<<BB, TT, 0, stream>>>(aligns, xlens, meta, inv_n, out);
  frame_kernel<<<BB * TT, BLOCK, 0, stream>>>(logits, ys, soft, meta, inv_n, out);
}

// Round 2
// 432.157 us; speedup vs baseline: 1.0187x; 1.0166x over previous
//
#include <hip/hip_runtime.h>
#include <math.h>

#define BB 16
#define TT 512
#define VV 8000
#define BLANK 0
#define LSM 0.1f
#define W_SOFT 0.5f
#define BLOCK 256

// Kernel 0: per-batch run scan -> meta[b*T+t] = (nonblank ? label_id : -1),
// inv_nexists[b] = 1/count(nonblank). Also zeroes d_out (re-poisoned each replay).
// Wave-shfl scan: 1 barrier instead of the 27 of Hillis-Steele — this kernel
// serializes before frame_kernel, so its latency is on the critical path.
__global__ __launch_bounds__(TT) void meta_kernel(
    const int* __restrict__ aligns,
    const int* __restrict__ xlens,
    int* __restrict__ meta,
    float* __restrict__ inv_nexists,
    float* __restrict__ out) {
  int b = blockIdx.x;
  int t = threadIdx.x;  // 512 threads, one per frame
  if (b == 0 && t == 0) out[0] = 0.0f;

  int xlen = xlens[b];
  int a  = (t < xlen) ? aligns[b * TT + t] : BLANK;
  int ap = BLANK;
  if (t > 0) ap = ((t - 1) < xlen) ? aligns[b * TT + t - 1] : BLANK;
  int nonblank = (a != BLANK) ? 1 : 0;
  int runstart = (nonblank && (a != ap)) ? 1 : 0;

  int lane = t & 63;
  int w = t >> 6;  // 8 waves

  // wave-level inclusive scan of runstart flags
  int val = runstart;
#pragma unroll
  for (int off = 1; off < 64; off <<= 1) {
    int v = __shfl_up(val, off);
    if (lane >= off) val += v;
  }
  // wave-level nonblank count
  int cnt = nonblank;
#pragma unroll
  for (int off = 32; off > 0; off >>= 1) cnt += __shfl_xor(cnt, off);

  __shared__ int wsum[8], wcnt[8];
  if (lane == 63) wsum[w] = val;
  if (lane == 0)  wcnt[w] = cnt;
  __syncthreads();

  int base = 0;
#pragma unroll
  for (int i = 0; i < 8; ++i) if (i < w) base += wsum[i];
  meta[b * TT + t] = nonblank ? (base + val - 1) : -1;

  if (t == 0) {
    int total = 0;
#pragma unroll
    for (int i = 0; i < 8; ++i) total += wcnt[i];
    inv_nexists[b] = 1.0f / (float)total;
  }
}

// Kernel 1: one block per (b,t) frame; blanks exit immediately.
// BOTH rows (logits + soft) are prefetched into registers at kernel top —
// one overlapped 64-KB HBM round trip per block instead of two serialized
// 32-KB ones (soft-row loads have no data dependence on the softmax; only
// the multiply does, but barriers' vmcnt(0) drain prevented hoisting when
// the loads sat in phase C).
__global__ __launch_bounds__(BLOCK) void frame_kernel(
    const float* __restrict__ logits,
    const int* __restrict__ ys,
    const float* __restrict__ soft,
    const int* __restrict__ meta,
    const float* __restrict__ inv_nexists,
    float* __restrict__ out) {
  int idx = blockIdx.x;
  int lm = meta[idx];
  if (lm < 0) return;
  int b = idx >> 9;  // / TT

  __shared__ float red[8];

  const float* xrow = logits + (size_t)idx * VV;
  const float* srow = soft + ((size_t)(b * TT + lm)) * VV;
  int tid = threadIdx.x;
  int wid = tid >> 6;

  // Prefetch both row streams into registers (16 outstanding float4/thread).
  float4 xr[8], sr[8];
#pragma unroll
  for (int k = 0; k < 8; ++k) {
    int i = tid * 4 + k * (BLOCK * 4);
    if (i < VV) {
      xr[k] = *(const float4*)(xrow + i);
      sr[k] = *(const float4*)(srow + i);
    } else {
      xr[k] = make_float4(-INFINITY, -INFINITY, -INFINITY, -INFINITY);
      sr[k] = make_float4(0.0f, 0.0f, 0.0f, 0.0f);
    }
  }
  // uniform prefetch of the hard label and x[y] (broadcast transactions)
  int y = ys[b * TT + lm];
  float xy = xrow[y];
  // pin all load issues above the reduction phases
  __builtin_amdgcn_sched_barrier(0);

  // Phase A: fused max + sum from registers (identical arithmetic order to r1)
  float tmax = -INFINITY, tsum = 0.0f;
#pragma unroll
  for (int k = 0; k < 8; ++k) {
    int i = tid * 4 + k * (BLOCK * 4);
    if (i < VV) {
      float4 x = xr[k];
      tmax = fmaxf(tmax, fmaxf(fmaxf(x.x, x.y), fmaxf(x.z, x.w)));
      tsum += (x.x + x.y) + (x.z + x.w);
    }
  }
  for (int off = 32; off > 0; off >>= 1) {
    tmax = fmaxf(tmax, __shfl_xor(tmax, off));
    tsum += __shfl_xor(tsum, off);
  }
  if ((tid & 63) == 0) { red[wid] = tmax; red[4 + wid] = tsum; }
  __syncthreads();
  float bmax = fmaxf(fmaxf(red[0], red[1]), fmaxf(red[2], red[3]));
  float bsum = (red[4] + red[5]) + (red[6] + red[7]);
  __syncthreads();

  // Phase B: sumexp from registers (exp(-INF - bmax) == 0, tail is harmless)
  float tse = 0.0f;
#pragma unroll
  for (int k = 0; k < 8; ++k) {
    tse += __expf(xr[k].x - bmax) + __expf(xr[k].y - bmax) +
           __expf(xr[k].z - bmax) + __expf(xr[k].w - bmax);
  }
  for (int off = 32; off > 0; off >>= 1) tse += __shfl_xor(tse, off);
  if ((tid & 63) == 0) red[wid] = tse;
  __syncthreads();
  float sumexp = (red[0] + red[1]) + (red[2] + red[3]);
  float C = bmax + logf(sumexp);   // logZ: logp[v] = x[v] - C
  __syncthreads();

  // Phase C: dot(soft_row, x - C) — both operands already in registers
  float tdot = 0.0f;
#pragma unroll
  for (int k = 0; k < 8; ++k) {
    int i = tid * 4 + k * (BLOCK * 4);
    if (i < VV) {
      float4 sv = sr[k];
      float4 x = xr[k];
      tdot += sv.x * (x.x - C) + sv.y * (x.y - C) +
              sv.z * (x.z - C) + sv.w * (x.w - C);
    }
  }
  for (int off = 32; off > 0; off >>= 1) tdot += __shfl_xor(tdot, off);
  if ((tid & 63) == 0) red[wid] = tdot;
  __syncthreads();

  if (tid == 0) {
    float dot = (red[0] + red[1]) + (red[2] + red[3]);
    float logp_y = xy - C;
    float sum_lp = bsum - (float)VV * C;
    float frame_hard = (1.0f - LSM) * logp_y +
                       (LSM / (float)(VV - 1)) * (sum_lp - logp_y);
    float val = W_SOFT * dot + (1.0f - W_SOFT) * frame_hard;
    atomicAdd(out, -val * inv_nexists[b] * (1.0f / (float)BB));
  }
}

extern "C" void kernel_launch(void* const* d_in, const int* in_sizes, int n_in,
                              void* d_out, int out_size, void* d_ws, size_t ws_size,
                              hipStream_t stream) {
  const float* logits = (const float*)d_in[0];
  const int*   ys     = (const int*)d_in[1];
  const float* soft   = (const float*)d_in[2];
  const int*   aligns = (const int*)d_in[3];
  const int*   xlens  = (const int*)d_in[4];
  // d_in[5] = ylens: unused by the reference math

  int*   meta  = (int*)d_ws;
  float* inv_n = (float*)((char*)d_ws + (size_t)BB * TT * sizeof(int));
  float* out   = (float*)d_out;

  meta_kernel<<<BB, TT, 0, stream>>>(aligns, xlens, meta, inv_n, out);
  frame_kernel<<<BB * TT, BLOCK, 0, stream>>>(logits, ys, soft, meta, inv_n, out);
}

// Round 3
// 431.322 us; speedup vs baseline: 1.0207x; 1.0019x over previous
//
#include <hip/hip_runtime.h>
#include <math.h>

#define BB 16
#define TT 512
#define VV 8000
#define BLANK 0
#define LSM 0.1f
#define W_SOFT 0.5f
#define BLOCK 256

// Single fused kernel: one block per (b,t) frame.
// - blank frames exit after two L2-cached scalar loads (no meta[] pass).
// - lm / n_exists are COUNTS (not scans): #runstarts in aligns[b][0..t] and
//   #nonblank in [0,xlen) — one packed block-reduction over a 2 KB L2-resident
//   slice, executed while the 32 KB logits prefetch is in flight.
// - both row streams register-staged; phase arithmetic identical to r2.
__global__ __launch_bounds__(BLOCK) void fused_kernel(
    const float* __restrict__ logits,
    const int* __restrict__ ys,
    const float* __restrict__ soft,
    const int* __restrict__ aligns,
    const int* __restrict__ xlens,
    float* __restrict__ out) {
  int idx = blockIdx.x;
  int b = idx >> 9;         // / TT
  int t = idx & (TT - 1);

  int xlen = xlens[b];
  if (t >= xlen) return;
  if (aligns[b * TT + t] == BLANK) return;   // blank frame: dead block

  int tid = threadIdx.x;
  int lane = tid & 63;
  int wid = tid >> 6;

  // ---- issue logits prefetch first (32 KB in flight during the scan) ----
  const float* xrow = logits + (size_t)idx * VV;
  float4 xr[8];
#pragma unroll
  for (int k = 0; k < 8; ++k) {
    int i = tid * 4 + k * (BLOCK * 4);
    if (i < VV) {
      xr[k] = *(const float4*)(xrow + i);
    } else {
      xr[k] = make_float4(-INFINITY, -INFINITY, -INFINITY, -INFINITY);
    }
  }

  // ---- packed reduction: lm (runstarts <= t) and n_exists (nonblank) ----
  // each thread covers frames j0 = 2*tid, j1 = 2*tid+1 (512 = 2*BLOCK)
  int j0 = tid * 2, j1 = tid * 2 + 1;
  int a0  = (j0 < xlen) ? aligns[b * TT + j0] : BLANK;
  int a1  = (j1 < xlen) ? aligns[b * TT + j1] : BLANK;
  int am1 = (j0 > 0 && (j0 - 1) < xlen) ? aligns[b * TT + j0 - 1] : BLANK;

  int rs0 = (a0 != BLANK && a0 != am1 && j0 <= t) ? 1 : 0;
  int rs1 = (a1 != BLANK && a1 != a0  && j1 <= t) ? 1 : 0;
  int nb  = (a0 != BLANK ? 1 : 0) + (a1 != BLANK ? 1 : 0);

  // pack: runstart count in high 16, nonblank count in low 16 (sums <= 512)
  int pack = ((rs0 + rs1) << 16) | nb;
#pragma unroll
  for (int off = 32; off > 0; off >>= 1) pack += __shfl_xor(pack, off);

  __shared__ int redi[4];
  __shared__ float red[8];
  if (lane == 0) redi[wid] = pack;
  __syncthreads();
  int tot = (redi[0] + redi[1]) + (redi[2] + redi[3]);
  int lm = (tot >> 16) - 1;                 // >= 0: frame t itself is a run member
  float inv_n = 1.0f / (float)(tot & 0xffff);
  __syncthreads();

  // ---- issue soft-row prefetch + uniform hard-label fetches ----
  const float* srow = soft + ((size_t)(b * TT + lm)) * VV;
  float4 sr[8];
#pragma unroll
  for (int k = 0; k < 8; ++k) {
    int i = tid * 4 + k * (BLOCK * 4);
    if (i < VV) {
      sr[k] = *(const float4*)(srow + i);
    } else {
      sr[k] = make_float4(0.0f, 0.0f, 0.0f, 0.0f);
    }
  }
  int y = ys[b * TT + lm];
  float xy = xrow[y];
  __builtin_amdgcn_sched_barrier(0);

  // Phase A: fused max + sum from registers (identical arithmetic order)
  float tmax = -INFINITY, tsum = 0.0f;
#pragma unroll
  for (int k = 0; k < 8; ++k) {
    int i = tid * 4 + k * (BLOCK * 4);
    if (i < VV) {
      float4 x = xr[k];
      tmax = fmaxf(tmax, fmaxf(fmaxf(x.x, x.y), fmaxf(x.z, x.w)));
      tsum += (x.x + x.y) + (x.z + x.w);
    }
  }
  for (int off = 32; off > 0; off >>= 1) {
    tmax = fmaxf(tmax, __shfl_xor(tmax, off));
    tsum += __shfl_xor(tsum, off);
  }
  if (lane == 0) { red[wid] = tmax; red[4 + wid] = tsum; }
  __syncthreads();
  float bmax = fmaxf(fmaxf(red[0], red[1]), fmaxf(red[2], red[3]));
  float bsum = (red[4] + red[5]) + (red[6] + red[7]);
  __syncthreads();

  // Phase B: sumexp from registers (exp(-INF - bmax) == 0, tail is harmless)
  float tse = 0.0f;
#pragma unroll
  for (int k = 0; k < 8; ++k) {
    tse += __expf(xr[k].x - bmax) + __expf(xr[k].y - bmax) +
           __expf(xr[k].z - bmax) + __expf(xr[k].w - bmax);
  }
  for (int off = 32; off > 0; off >>= 1) tse += __shfl_xor(tse, off);
  if (lane == 0) red[wid] = tse;
  __syncthreads();
  float sumexp = (red[0] + red[1]) + (red[2] + red[3]);
  float C = bmax + logf(sumexp);   // logZ: logp[v] = x[v] - C
  __syncthreads();

  // Phase C: dot(soft_row, x - C) — both operands in registers
  float tdot = 0.0f;
#pragma unroll
  for (int k = 0; k < 8; ++k) {
    int i = tid * 4 + k * (BLOCK * 4);
    if (i < VV) {
      float4 sv = sr[k];
      float4 x = xr[k];
      tdot += sv.x * (x.x - C) + sv.y * (x.y - C) +
              sv.z * (x.z - C) + sv.w * (x.w - C);
    }
  }
  for (int off = 32; off > 0; off >>= 1) tdot += __shfl_xor(tdot, off);
  if (lane == 0) red[wid] = tdot;
  __syncthreads();

  if (tid == 0) {
    float dot = (red[0] + red[1]) + (red[2] + red[3]);
    float logp_y = xy - C;
    float sum_lp = bsum - (float)VV * C;
    float frame_hard = (1.0f - LSM) * logp_y +
                       (LSM / (float)(VV - 1)) * (sum_lp - logp_y);
    float val = W_SOFT * dot + (1.0f - W_SOFT) * frame_hard;
    atomicAdd(out, -val * inv_n * (1.0f / (float)BB));
  }
}

extern "C" void kernel_launch(void* const* d_in, const int* in_sizes, int n_in,
                              void* d_out, int out_size, void* d_ws, size_t ws_size,
                              hipStream_t stream) {
  const float* logits = (const float*)d_in[0];
  const int*   ys     = (const int*)d_in[1];
  const float* soft   = (const float*)d_in[2];
  const int*   aligns = (const int*)d_in[3];
  const int*   xlens  = (const int*)d_in[4];
  // d_in[5] = ylens: unused by the reference math

  float* out = (float*)d_out;
  // zero the (re-poisoned) output; stream-ordered, graph-capture-safe
  hipMemsetAsync(out, 0, sizeof(float), stream);
  fused_kernel<<<BB * TT, BLOCK, 0, stream>>>(logits, ys, soft, aligns, xlens, out);
}